// Round 1
// baseline (1624.525 us; speedup 1.0000x reference)
//
#include <hip/hip_runtime.h>
#include <cstdint>
#include <cstddef>

#define TLEN 512
#define BATCH 1000
#define NEV 102400
#define HID 64

__device__ __forceinline__ float fast_rcp(float x) {
#if __has_builtin(__builtin_amdgcn_rcpf)
    return __builtin_amdgcn_rcpf(x);
#else
    return 1.0f / x;
#endif
}
__device__ __forceinline__ float sigm(float x) { return fast_rcp(1.0f + __expf(-x)); }
__device__ __forceinline__ float tanh_f(float x) { return fmaf(2.0f, sigm(2.0f * x), -1.0f); }

// ---------------------------------------------------------------------------
// Embed one source: out[h] = b[h] + sum_j x[j] * W[j,h],
// x = concat(tab[cat[e,0..ncat-1]] (8 each), num[e,0..nnum-1])
// scatter to feat[bi[e]*T + ti[e]][h].  4 events per 256-thread block.
// ---------------------------------------------------------------------------
__global__ __launch_bounds__(256) void embed_kernel(
    const float* __restrict__ num, const int* __restrict__ cat,
    const float* __restrict__ tab, const int* __restrict__ bi,
    const int* __restrict__ ti, const float* __restrict__ W,
    const float* __restrict__ bvec, float* __restrict__ feat,
    int n_num, int n_cat)
{
    int e = blockIdx.x * 4 + (threadIdx.x >> 6);
    int hh = threadIdx.x & 63;
    if (e >= NEV) return;
    float acc = bvec[hh];
    int j = 0;
    for (int c = 0; c < n_cat; ++c) {
        int idx = cat[e * n_cat + c];
        const float* trow = tab + (size_t)idx * 8;
#pragma unroll
        for (int u = 0; u < 8; ++u)
            acc = fmaf(trow[u], W[(j + u) * HID + hh], acc);
        j += 8;
    }
    for (int u = 0; u < n_num; ++u)
        acc = fmaf(num[(size_t)e * n_num + u], W[(j + u) * HID + hh], acc);
    int pos = bi[e] * TLEN + ti[e];
    feat[(size_t)pos * HID + hh] = acc;
}

// ---------------------------------------------------------------------------
// LSTM layer 0: one block per (batch, dir). 256 threads; thread owns gate
// row tid (Wih row in 64 VGPRs). Per step: feat[b,t,:] staged in LDS
// (double-buffered), g computed and exchanged via LDS, all 4 waves
// redundantly update cell state c[lane] and wave-reduce h (scalar, proj=1).
// ---------------------------------------------------------------------------
__global__ __launch_bounds__(256) void lstm0_kernel(
    const float* __restrict__ feat, const float* __restrict__ Wih,
    const float* __restrict__ Whh, const float* __restrict__ Whr,
    const float* __restrict__ bih, const float* __restrict__ bhh,
    float* __restrict__ h0)
{
    int blk = blockIdx.x;
    int b = blk >> 1, dir = blk & 1;
    int tid = threadIdx.x, lane = tid & 63;

    const float* wrow = Wih + (size_t)(dir * 256 + tid) * HID;
    float4 w[16];
#pragma unroll
    for (int i = 0; i < 16; ++i) w[i] = ((const float4*)wrow)[i];
    float whh = Whh[dir * 256 + tid];
    float bias = bih[dir * 256 + tid] + bhh[dir * 256 + tid];
    float whr = Whr[dir * HID + lane];

    __shared__ float4 featb[2][16];
    __shared__ float gbuf[2][256];

    float c = 0.0f, h = 0.0f;
    const float* fb = feat + (size_t)b * TLEN * HID;

    int tt0 = dir ? (TLEN - 1) : 0;
    if (tid < 64) ((float*)featb[0])[tid] = fb[(size_t)tt0 * HID + tid];
    __syncthreads();

    for (int t = 0; t < TLEN; ++t) {
        int buf = t & 1;
        int tt = dir ? (TLEN - 1 - t) : t;
        // prefetch next step's feat into registers (no dependence on h)
        float nf = 0.0f;
        int tn = dir ? (TLEN - 2 - t) : (t + 1);
        bool pf = (tid < 64) && (t < TLEN - 1);
        if (pf) nf = fb[(size_t)tn * HID + tid];

        // g[row] = bias + Whh[row]*h + sum_j feat[j]*Wih[row,j]
        float acc = fmaf(whh, h, bias);
#pragma unroll
        for (int i = 0; i < 16; ++i) {
            float4 f4 = featb[buf][i];  // wave-uniform address -> LDS broadcast
            acc = fmaf(f4.x, w[i].x, acc);
            acc = fmaf(f4.y, w[i].y, acc);
            acc = fmaf(f4.z, w[i].z, acc);
            acc = fmaf(f4.w, w[i].w, acc);
        }
        gbuf[buf][tid] = acc;
        if (pf) ((float*)featb[1 - buf])[tid] = nf;
        __syncthreads();

        // cell update, redundantly in every wave (each wave keeps its own c)
        float gi = gbuf[buf][lane];
        float gf = gbuf[buf][64 + lane];
        float gg = gbuf[buf][128 + lane];
        float go = gbuf[buf][192 + lane];
        c = sigm(gf) * c + sigm(gi) * tanh_f(gg);
        float p = sigm(go) * tanh_f(c) * whr;
#pragma unroll
        for (int off = 1; off < 64; off <<= 1) p += __shfl_xor(p, off, 64);
        h = p;
        if (tid == 0) h0[((size_t)b * TLEN + tt) * 2 + dir] = h;
    }
}

// ---------------------------------------------------------------------------
// LSTM layer 1: insz=2. One wave per (batch, dir); lane owns cell `lane`
// and the 4 gate rows {64k+lane}. 4 waves (4 pairs) per block.
// ---------------------------------------------------------------------------
__global__ __launch_bounds__(256) void lstm1_kernel(
    const float* __restrict__ h0, const float* __restrict__ Wih,
    const float* __restrict__ Whh, const float* __restrict__ Whr,
    const float* __restrict__ bih, const float* __restrict__ bhh,
    float* __restrict__ h1)
{
    int w = threadIdx.x >> 6, lane = threadIdx.x & 63;
    int p = blockIdx.x * 4 + w;  // 0..1999
    int b = p >> 1, dir = p & 1;

    float wi0[4], wi1[4], whh[4], bias[4];
#pragma unroll
    for (int k = 0; k < 4; ++k) {
        int r = k * 64 + lane;
        wi0[k] = Wih[(size_t)(dir * 256 + r) * 2 + 0];
        wi1[k] = Wih[(size_t)(dir * 256 + r) * 2 + 1];
        whh[k] = Whh[dir * 256 + r];
        bias[k] = bih[dir * 256 + r] + bhh[dir * 256 + r];
    }
    float whr = Whr[dir * HID + lane];
    float h = 0.0f, c = 0.0f;
    const float* hb = h0 + (size_t)b * TLEN * 2;

    for (int t = 0; t < TLEN; ++t) {
        int tt = dir ? (TLEN - 1 - t) : t;
        float x0 = hb[tt * 2], x1 = hb[tt * 2 + 1];
        float g[4];
#pragma unroll
        for (int k = 0; k < 4; ++k)
            g[k] = fmaf(whh[k], h, fmaf(wi1[k], x1, fmaf(wi0[k], x0, bias[k])));
        c = sigm(g[1]) * c + sigm(g[0]) * tanh_f(g[2]);
        float pp = sigm(g[3]) * tanh_f(c) * whr;
#pragma unroll
        for (int off = 1; off < 64; off <<= 1) pp += __shfl_xor(pp, off, 64);
        h = pp;
        if (lane == 0) h1[((size_t)b * TLEN + tt) * 2 + dir] = h;
    }
}

// ---------------------------------------------------------------------------
// out[i] = mean over last dim of h1[B,T,2]
// ---------------------------------------------------------------------------
__global__ __launch_bounds__(256) void mean_kernel(
    const float2* __restrict__ h1, float* __restrict__ out)
{
    int i = blockIdx.x * 256 + threadIdx.x;
    if (i < BATCH * TLEN) {
        float2 v = h1[i];
        out[i] = 0.5f * (v.x + v.y);
    }
}

extern "C" void kernel_launch(void* const* d_in, const int* in_sizes, int n_in,
                              void* d_out, int out_size, void* d_ws, size_t ws_size,
                              hipStream_t stream)
{
    // input indices (setup_inputs order)
    const float* ccba_num = (const float*)d_in[0];
    const int*   ccba_bi  = (const int*)d_in[1];
    const int*   ccba_ti  = (const int*)d_in[2];
    const float* ccba_W   = (const float*)d_in[3];
    const float* ccba_b   = (const float*)d_in[4];
    const float* cdtx_num = (const float*)d_in[5];
    const int*   cdtx_cat = (const int*)d_in[6];
    const float* cdtx_tab = (const float*)d_in[7];
    const int*   cdtx_bi  = (const int*)d_in[8];
    const int*   cdtx_ti  = (const int*)d_in[9];
    const float* cdtx_W   = (const float*)d_in[10];
    const float* cdtx_b   = (const float*)d_in[11];
    const float* cust_num = (const float*)d_in[12];
    const int*   cust_cat = (const int*)d_in[13];
    const float* cust_tab = (const float*)d_in[14];
    const int*   cust_bi  = (const int*)d_in[15];
    const int*   cust_ti  = (const int*)d_in[16];
    const float* cust_W   = (const float*)d_in[17];
    const float* cust_b   = (const float*)d_in[18];
    const float* dp_num   = (const float*)d_in[19];
    const int*   dp_cat   = (const int*)d_in[20];
    const float* dp_tab   = (const float*)d_in[21];
    const int*   dp_bi    = (const int*)d_in[22];
    const int*   dp_ti    = (const int*)d_in[23];
    const float* dp_W     = (const float*)d_in[24];
    const float* dp_b     = (const float*)d_in[25];
    const float* remit_num = (const float*)d_in[26];
    const int*   remit_cat = (const int*)d_in[27];
    const float* remit_tab = (const float*)d_in[28];
    const int*   remit_bi  = (const int*)d_in[29];
    const int*   remit_ti  = (const int*)d_in[30];
    const float* remit_W   = (const float*)d_in[31];
    const float* remit_b   = (const float*)d_in[32];
    const float* Wih0 = (const float*)d_in[33];
    const float* Whh0 = (const float*)d_in[34];
    const float* Whr0 = (const float*)d_in[35];
    const float* bih0 = (const float*)d_in[36];
    const float* bhh0 = (const float*)d_in[37];
    const float* Wih1 = (const float*)d_in[38];
    const float* Whh1 = (const float*)d_in[39];
    const float* Whr1 = (const float*)d_in[40];
    const float* bih1 = (const float*)d_in[41];
    const float* bhh1 = (const float*)d_in[42];

    // workspace layout
    char* ws = (char*)d_ws;
    float* feat = (float*)ws;                          // 512000*64*4 = 131072000 B
    float* h0   = (float*)(ws + 131072000);            // 512000*2*4  =   4096000 B
    float* h1   = (float*)(ws + 135168000);            // 512000*2*4  =   4096000 B
    float* out  = (float*)d_out;                       // 512000 fp32

    dim3 blk(256);
    int eg = (NEV + 3) / 4;  // 4 events per block

    embed_kernel<<<eg, blk, 0, stream>>>(ccba_num, nullptr, nullptr, ccba_bi, ccba_ti, ccba_W, ccba_b, feat, 8, 0);
    embed_kernel<<<eg, blk, 0, stream>>>(cdtx_num, cdtx_cat, cdtx_tab, cdtx_bi, cdtx_ti, cdtx_W, cdtx_b, feat, 1, 2);
    embed_kernel<<<eg, blk, 0, stream>>>(cust_num, cust_cat, cust_tab, cust_bi, cust_ti, cust_W, cust_b, feat, 1, 3);
    embed_kernel<<<eg, blk, 0, stream>>>(dp_num, dp_cat, dp_tab, dp_bi, dp_ti, dp_W, dp_b, feat, 2, 8);
    embed_kernel<<<eg, blk, 0, stream>>>(remit_num, remit_cat, remit_tab, remit_bi, remit_ti, remit_W, remit_b, feat, 1, 1);

    lstm0_kernel<<<BATCH * 2, blk, 0, stream>>>(feat, Wih0, Whh0, Whr0, bih0, bhh0, h0);
    lstm1_kernel<<<(BATCH * 2) / 4, blk, 0, stream>>>(h0, Wih1, Whh1, Whr1, bih1, bhh1, h1);
    mean_kernel<<<(BATCH * TLEN + 255) / 256, blk, 0, stream>>>((const float2*)h1, out);
}

// Round 2
// 1566.775 us; speedup vs baseline: 1.0369x; 1.0369x over previous
//
#include <hip/hip_runtime.h>
#include <cstdint>
#include <cstddef>

#define TLEN 512
#define BATCH 1000
#define NEV 102400
#define HID 64

__device__ __forceinline__ float fast_rcp(float x) {
#if __has_builtin(__builtin_amdgcn_rcpf)
    return __builtin_amdgcn_rcpf(x);
#else
    return 1.0f / x;
#endif
}
__device__ __forceinline__ float sigm(float x) { return fast_rcp(1.0f + __expf(-x)); }
__device__ __forceinline__ float tanh_f(float x) { return fmaf(2.0f, sigm(2.0f * x), -1.0f); }

// ---------------------------------------------------------------------------
// Embed one source: out[h] = b[h] + sum_j x[j] * W[j,h],
// scatter to feat[bi[e]*T + ti[e]][h].  4 events per 256-thread block.
// ---------------------------------------------------------------------------
__global__ __launch_bounds__(256) void embed_kernel(
    const float* __restrict__ num, const int* __restrict__ cat,
    const float* __restrict__ tab, const int* __restrict__ bi,
    const int* __restrict__ ti, const float* __restrict__ W,
    const float* __restrict__ bvec, float* __restrict__ feat,
    int n_num, int n_cat)
{
    int e = blockIdx.x * 4 + (threadIdx.x >> 6);
    int hh = threadIdx.x & 63;
    if (e >= NEV) return;
    float acc = bvec[hh];
    int j = 0;
    for (int c = 0; c < n_cat; ++c) {
        int idx = cat[e * n_cat + c];
        const float* trow = tab + (size_t)idx * 8;
#pragma unroll
        for (int u = 0; u < 8; ++u)
            acc = fmaf(trow[u], W[(j + u) * HID + hh], acc);
        j += 8;
    }
    for (int u = 0; u < n_num; ++u)
        acc = fmaf(num[(size_t)e * n_num + u], W[(j + u) * HID + hh], acc);
    int pos = bi[e] * TLEN + ti[e];
    feat[(size_t)pos * HID + hh] = acc;
}

// ---------------------------------------------------------------------------
// LSTM layer 0 v2: one block = 4 batches x 1 direction. 256 threads.
// Thread tid owns gate row tid (Wih row in 64 VGPRs) and computes that
// row's gate for 4 batches per step (4 indep accumulators). Wave w does
// batch w's cell update exactly once (non-redundant); h broadcast via LDS.
// ---------------------------------------------------------------------------
__global__ __launch_bounds__(256, 2) void lstm0_kernel(
    const float* __restrict__ feat, const float* __restrict__ Wih,
    const float* __restrict__ Whh, const float* __restrict__ Whr,
    const float* __restrict__ bih, const float* __restrict__ bhh,
    float* __restrict__ h0)
{
    const int b0 = blockIdx.x * 4;
    const int dir = blockIdx.y;
    const int tid = threadIdx.x, lane = tid & 63, wv = tid >> 6;

    const float* wrow = Wih + (size_t)(dir * 256 + tid) * HID;
    float4 w[16];
#pragma unroll
    for (int i = 0; i < 16; ++i) w[i] = ((const float4*)wrow)[i];
    const float whh = Whh[dir * 256 + tid];
    const float bias = bih[dir * 256 + tid] + bhh[dir * 256 + tid];
    const float whr = Whr[dir * HID + lane];

    __shared__ float4 featb[2][4][16];      // [buf][batch][16 float4]
    __shared__ float gbuf[4][256];          // [batch][gate row]
    __shared__ __align__(16) float hbuf[4]; // per-batch projected hidden

    float c = 0.0f;                         // wave wv's cell for batch wv
    const float* fb = feat + (size_t)(b0 + wv) * TLEN * HID; // batch wv, elem lane
    float* h0b = h0 + ((size_t)(b0 + wv) * TLEN) * 2 + dir;

    // stage first timestep's feat: thread (wv, lane) -> featb[0][wv][lane]
    const int t0 = dir ? (TLEN - 1) : 0;
    ((float*)featb[0][wv])[lane] = fb[(size_t)t0 * HID + lane];
    if (tid < 4) hbuf[tid] = 0.0f;
    __syncthreads();

    for (int t = 0; t < TLEN; ++t) {
        const int buf = t & 1;
        const int tt = dir ? (TLEN - 1 - t) : t;

        // prefetch next step's feat into registers (independent of h)
        float nf = 0.0f;
        const int tn = dir ? (TLEN - 2 - t) : (t + 1);
        const bool pf = (t < TLEN - 1);
        if (pf) nf = fb[(size_t)tn * HID + lane];

        // previous h for all 4 batches (one uniform b128 read)
        const float4 hp = *(const float4*)hbuf;

        float a0 = fmaf(whh, hp.x, bias);
        float a1 = fmaf(whh, hp.y, bias);
        float a2 = fmaf(whh, hp.z, bias);
        float a3 = fmaf(whh, hp.w, bias);
#pragma unroll
        for (int i = 0; i < 16; ++i) {
            float4 f0 = featb[buf][0][i];   // wave-uniform -> LDS broadcast
            float4 f1 = featb[buf][1][i];
            float4 f2 = featb[buf][2][i];
            float4 f3 = featb[buf][3][i];
            a0 = fmaf(f0.x, w[i].x, a0); a0 = fmaf(f0.y, w[i].y, a0);
            a0 = fmaf(f0.z, w[i].z, a0); a0 = fmaf(f0.w, w[i].w, a0);
            a1 = fmaf(f1.x, w[i].x, a1); a1 = fmaf(f1.y, w[i].y, a1);
            a1 = fmaf(f1.z, w[i].z, a1); a1 = fmaf(f1.w, w[i].w, a1);
            a2 = fmaf(f2.x, w[i].x, a2); a2 = fmaf(f2.y, w[i].y, a2);
            a2 = fmaf(f2.z, w[i].z, a2); a2 = fmaf(f2.w, w[i].w, a2);
            a3 = fmaf(f3.x, w[i].x, a3); a3 = fmaf(f3.y, w[i].y, a3);
            a3 = fmaf(f3.z, w[i].z, a3); a3 = fmaf(f3.w, w[i].w, a3);
        }
        gbuf[0][tid] = a0;
        gbuf[1][tid] = a1;
        gbuf[2][tid] = a2;
        gbuf[3][tid] = a3;
        if (pf) ((float*)featb[1 - buf][wv])[lane] = nf;
        __syncthreads();

        // wave wv updates batch wv's cell (non-redundant)
        const float gi = gbuf[wv][lane];
        const float gf = gbuf[wv][64 + lane];
        const float gg = gbuf[wv][128 + lane];
        const float go = gbuf[wv][192 + lane];
        c = sigm(gf) * c + sigm(gi) * tanh_f(gg);
        float p = sigm(go) * tanh_f(c) * whr;
#pragma unroll
        for (int off = 1; off < 64; off <<= 1) p += __shfl_xor(p, off, 64);
        if (lane == 0) {
            hbuf[wv] = p;
            h0b[(size_t)tt * 2] = p;
        }
        __syncthreads();
    }
}

// ---------------------------------------------------------------------------
// LSTM layer 1: insz=2. One wave per (batch, dir); lane owns cell `lane`
// and the 4 gate rows {64k+lane}. 4 waves (4 pairs) per block.
// ---------------------------------------------------------------------------
__global__ __launch_bounds__(256) void lstm1_kernel(
    const float* __restrict__ h0, const float* __restrict__ Wih,
    const float* __restrict__ Whh, const float* __restrict__ Whr,
    const float* __restrict__ bih, const float* __restrict__ bhh,
    float* __restrict__ h1)
{
    int w = threadIdx.x >> 6, lane = threadIdx.x & 63;
    int p = blockIdx.x * 4 + w;  // 0..1999
    int b = p >> 1, dir = p & 1;

    float wi0[4], wi1[4], whh[4], bias[4];
#pragma unroll
    for (int k = 0; k < 4; ++k) {
        int r = k * 64 + lane;
        wi0[k] = Wih[(size_t)(dir * 256 + r) * 2 + 0];
        wi1[k] = Wih[(size_t)(dir * 256 + r) * 2 + 1];
        whh[k] = Whh[dir * 256 + r];
        bias[k] = bih[dir * 256 + r] + bhh[dir * 256 + r];
    }
    float whr = Whr[dir * HID + lane];
    float h = 0.0f, c = 0.0f;
    const float* hb = h0 + (size_t)b * TLEN * 2;

    for (int t = 0; t < TLEN; ++t) {
        int tt = dir ? (TLEN - 1 - t) : t;
        float x0 = hb[tt * 2], x1 = hb[tt * 2 + 1];
        float g[4];
#pragma unroll
        for (int k = 0; k < 4; ++k)
            g[k] = fmaf(whh[k], h, fmaf(wi1[k], x1, fmaf(wi0[k], x0, bias[k])));
        c = sigm(g[1]) * c + sigm(g[0]) * tanh_f(g[2]);
        float pp = sigm(g[3]) * tanh_f(c) * whr;
#pragma unroll
        for (int off = 1; off < 64; off <<= 1) pp += __shfl_xor(pp, off, 64);
        h = pp;
        if (lane == 0) h1[((size_t)b * TLEN + tt) * 2 + dir] = h;
    }
}

// ---------------------------------------------------------------------------
// out[i] = mean over last dim of h1[B,T,2]
// ---------------------------------------------------------------------------
__global__ __launch_bounds__(256) void mean_kernel(
    const float2* __restrict__ h1, float* __restrict__ out)
{
    int i = blockIdx.x * 256 + threadIdx.x;
    if (i < BATCH * TLEN) {
        float2 v = h1[i];
        out[i] = 0.5f * (v.x + v.y);
    }
}

extern "C" void kernel_launch(void* const* d_in, const int* in_sizes, int n_in,
                              void* d_out, int out_size, void* d_ws, size_t ws_size,
                              hipStream_t stream)
{
    const float* ccba_num = (const float*)d_in[0];
    const int*   ccba_bi  = (const int*)d_in[1];
    const int*   ccba_ti  = (const int*)d_in[2];
    const float* ccba_W   = (const float*)d_in[3];
    const float* ccba_b   = (const float*)d_in[4];
    const float* cdtx_num = (const float*)d_in[5];
    const int*   cdtx_cat = (const int*)d_in[6];
    const float* cdtx_tab = (const float*)d_in[7];
    const int*   cdtx_bi  = (const int*)d_in[8];
    const int*   cdtx_ti  = (const int*)d_in[9];
    const float* cdtx_W   = (const float*)d_in[10];
    const float* cdtx_b   = (const float*)d_in[11];
    const float* cust_num = (const float*)d_in[12];
    const int*   cust_cat = (const int*)d_in[13];
    const float* cust_tab = (const float*)d_in[14];
    const int*   cust_bi  = (const int*)d_in[15];
    const int*   cust_ti  = (const int*)d_in[16];
    const float* cust_W   = (const float*)d_in[17];
    const float* cust_b   = (const float*)d_in[18];
    const float* dp_num   = (const float*)d_in[19];
    const int*   dp_cat   = (const int*)d_in[20];
    const float* dp_tab   = (const float*)d_in[21];
    const int*   dp_bi    = (const int*)d_in[22];
    const int*   dp_ti    = (const int*)d_in[23];
    const float* dp_W     = (const float*)d_in[24];
    const float* dp_b     = (const float*)d_in[25];
    const float* remit_num = (const float*)d_in[26];
    const int*   remit_cat = (const int*)d_in[27];
    const float* remit_tab = (const float*)d_in[28];
    const int*   remit_bi  = (const int*)d_in[29];
    const int*   remit_ti  = (const int*)d_in[30];
    const float* remit_W   = (const float*)d_in[31];
    const float* remit_b   = (const float*)d_in[32];
    const float* Wih0 = (const float*)d_in[33];
    const float* Whh0 = (const float*)d_in[34];
    const float* Whr0 = (const float*)d_in[35];
    const float* bih0 = (const float*)d_in[36];
    const float* bhh0 = (const float*)d_in[37];
    const float* Wih1 = (const float*)d_in[38];
    const float* Whh1 = (const float*)d_in[39];
    const float* Whr1 = (const float*)d_in[40];
    const float* bih1 = (const float*)d_in[41];
    const float* bhh1 = (const float*)d_in[42];

    char* ws = (char*)d_ws;
    float* feat = (float*)ws;                // 131072000 B
    float* h0   = (float*)(ws + 131072000);  // 4096000 B
    float* h1   = (float*)(ws + 135168000);  // 4096000 B
    float* out  = (float*)d_out;

    dim3 blk(256);
    int eg = (NEV + 3) / 4;

    embed_kernel<<<eg, blk, 0, stream>>>(ccba_num, nullptr, nullptr, ccba_bi, ccba_ti, ccba_W, ccba_b, feat, 8, 0);
    embed_kernel<<<eg, blk, 0, stream>>>(cdtx_num, cdtx_cat, cdtx_tab, cdtx_bi, cdtx_ti, cdtx_W, cdtx_b, feat, 1, 2);
    embed_kernel<<<eg, blk, 0, stream>>>(cust_num, cust_cat, cust_tab, cust_bi, cust_ti, cust_W, cust_b, feat, 1, 3);
    embed_kernel<<<eg, blk, 0, stream>>>(dp_num, dp_cat, dp_tab, dp_bi, dp_ti, dp_W, dp_b, feat, 2, 8);
    embed_kernel<<<eg, blk, 0, stream>>>(remit_num, remit_cat, remit_tab, remit_bi, remit_ti, remit_W, remit_b, feat, 1, 1);

    lstm0_kernel<<<dim3(BATCH / 4, 2), blk, 0, stream>>>(feat, Wih0, Whh0, Whr0, bih0, bhh0, h0);
    lstm1_kernel<<<(BATCH * 2) / 4, blk, 0, stream>>>(h0, Wih1, Whh1, Whr1, bih1, bhh1, h1);
    mean_kernel<<<(BATCH * TLEN + 255) / 256, blk, 0, stream>>>((const float2*)h1, out);
}

// Round 3
// 1561.895 us; speedup vs baseline: 1.0401x; 1.0031x over previous
//
#include <hip/hip_runtime.h>
#include <cstdint>
#include <cstddef>

#define TLEN 512
#define BATCH 1000
#define NEV 102400
#define HID 64

__device__ __forceinline__ float fast_rcp(float x) {
#if __has_builtin(__builtin_amdgcn_rcpf)
    return __builtin_amdgcn_rcpf(x);
#else
    return 1.0f / x;
#endif
}
__device__ __forceinline__ float sigm(float x) { return fast_rcp(1.0f + __expf(-x)); }
__device__ __forceinline__ float tanh_f(float x) { return fmaf(2.0f, sigm(2.0f * x), -1.0f); }

// ===========================================================================
// NEW PATH: composed projection -> materialized g_pre -> light recurrence
// ===========================================================================

// W'[row][col] for row = (src, j) [130 rows], col = dir*256 + gate_row [512].
// row j<IND: W_src[j] . Wih0[col];  row j==IND: b_src . Wih0[col] + bih+bhh.
__global__ __launch_bounds__(512) void compose_kernel(
    const float* __restrict__ W0, const float* __restrict__ B0,
    const float* __restrict__ W1, const float* __restrict__ B1,
    const float* __restrict__ W2, const float* __restrict__ B2,
    const float* __restrict__ W3, const float* __restrict__ B3,
    const float* __restrict__ W4, const float* __restrict__ B4,
    const float* __restrict__ Wih, const float* __restrict__ bih,
    const float* __restrict__ bhh, float* __restrict__ wp)
{
    const int col = threadIdx.x;   // 0..511 == dir*256 + r == Wih row index
    const int row = blockIdx.x;    // 0..129
    const float* srcW; const float* srcB; int base, IND;
    if (row < 9)        { srcW = W0; srcB = B0; base = 0;   IND = 8;  }
    else if (row < 27)  { srcW = W1; srcB = B1; base = 9;   IND = 17; }
    else if (row < 53)  { srcW = W2; srcB = B2; base = 27;  IND = 25; }
    else if (row < 120) { srcW = W3; srcB = B3; base = 53;  IND = 66; }
    else                { srcW = W4; srcB = B4; base = 120; IND = 9;  }
    const int j = row - base;
    const float* xrow = (j < IND) ? (srcW + (size_t)j * 64) : srcB;
    const float* wr = Wih + (size_t)col * 64;
    float acc = 0.0f;
#pragma unroll
    for (int h2 = 0; h2 < 64; ++h2) acc = fmaf(xrow[h2], wr[h2], acc);
    if (j == IND) acc += bih[col] + bhh[col];
    wp[(size_t)row * 512 + col] = acc;
}

// Per source: g_pre[pos, col] = b'[col] + sum_j x_e[j] * W'[j][col].
// x gathered via block-uniform (scalar) loads; W' column in VGPRs.
template<int NNUM, int NCAT>
__global__ __launch_bounds__(512) void project_kernel(
    const float* __restrict__ num, const int* __restrict__ cat,
    const float* __restrict__ tab, const int* __restrict__ bi,
    const int* __restrict__ ti, const float* __restrict__ wp,
    float* __restrict__ gpre)
{
    constexpr int IND = NCAT * 8 + NNUM;
    const int col = threadIdx.x;
    float wcol[IND];
#pragma unroll
    for (int j = 0; j < IND; ++j) wcol[j] = wp[(size_t)j * 512 + col];
    const float bcol = wp[(size_t)IND * 512 + col];

    for (int ev = blockIdx.x; ev < NEV; ev += gridDim.x) {
        const int pos = bi[ev] * TLEN + ti[ev];
        float acc = bcol;
#pragma unroll
        for (int c0 = 0; c0 < NCAT; ++c0) {
            const int idx = cat[ev * NCAT + c0];
            const float* tr = tab + (size_t)idx * 8;
#pragma unroll
            for (int u = 0; u < 8; ++u)
                acc = fmaf(tr[u], wcol[c0 * 8 + u], acc);
        }
#pragma unroll
        for (int u = 0; u < NNUM; ++u)
            acc = fmaf(num[(size_t)ev * NNUM + u], wcol[NCAT * 8 + u], acc);
        gpre[(size_t)pos * 512 + col] = acc;
    }
}

// Recurrence over precomputed gates. One wave per (b,dir); lane = cell.
// g_pre loads prefetched 2 steps ahead (independent of recurrence).
__global__ __launch_bounds__(256) void rec0_kernel(
    const float* __restrict__ gpre, const float* __restrict__ Whh,
    const float* __restrict__ Whr, float* __restrict__ h0)
{
    const int wv = threadIdx.x >> 6, lane = threadIdx.x & 63;
    const int p = blockIdx.x * 4 + wv;
    const int b = p >> 1, dir = p & 1;

    float whh4[4];
#pragma unroll
    for (int k = 0; k < 4; ++k) whh4[k] = Whh[dir * 256 + k * 64 + lane];
    const float whr = Whr[dir * HID + lane];

    const float* gb = gpre + (size_t)dir * 256 + lane;
    float* h0p = h0 + (size_t)b * TLEN * 2 + dir;

    auto addr = [&](int t) -> const float* {
        int tc = t < TLEN ? t : TLEN - 1;           // clamp (value unused past end)
        int tt = dir ? (TLEN - 1 - tc) : tc;
        return gb + ((size_t)(b * TLEN + tt)) * 512;
    };

    float A[4], B[4];
    {
        const float* pa = addr(0); const float* pb = addr(1);
#pragma unroll
        for (int k = 0; k < 4; ++k) { A[k] = pa[k * 64]; B[k] = pb[k * 64]; }
    }
    float h = 0.0f, c = 0.0f;

    for (int t = 0; t < TLEN; t += 2) {
        float C[4], D[4];
        const float* pc = addr(t + 2); const float* pd = addr(t + 3);
#pragma unroll
        for (int k = 0; k < 4; ++k) { C[k] = pc[k * 64]; D[k] = pd[k * 64]; }

        // step t
        {
            float gi = fmaf(whh4[0], h, A[0]);
            float gf = fmaf(whh4[1], h, A[1]);
            float gg = fmaf(whh4[2], h, A[2]);
            float go = fmaf(whh4[3], h, A[3]);
            c = sigm(gf) * c + sigm(gi) * tanh_f(gg);
            float pp = sigm(go) * tanh_f(c) * whr;
#pragma unroll
            for (int off = 1; off < 64; off <<= 1) pp += __shfl_xor(pp, off, 64);
            h = pp;
            int tt = dir ? (TLEN - 1 - t) : t;
            if (lane == 0) h0p[(size_t)tt * 2] = h;
        }
        // step t+1
        {
            float gi = fmaf(whh4[0], h, B[0]);
            float gf = fmaf(whh4[1], h, B[1]);
            float gg = fmaf(whh4[2], h, B[2]);
            float go = fmaf(whh4[3], h, B[3]);
            c = sigm(gf) * c + sigm(gi) * tanh_f(gg);
            float pp = sigm(go) * tanh_f(c) * whr;
#pragma unroll
            for (int off = 1; off < 64; off <<= 1) pp += __shfl_xor(pp, off, 64);
            h = pp;
            int tt = dir ? (TLEN - 2 - t) : (t + 1);
            if (lane == 0) h0p[(size_t)tt * 2] = h;
        }
#pragma unroll
        for (int k = 0; k < 4; ++k) { A[k] = C[k]; B[k] = D[k]; }
    }
}

// ===========================================================================
// LSTM layer 1 (insz=2), with 2-step x prefetch. One wave per (b,dir).
// ===========================================================================
__global__ __launch_bounds__(256) void lstm1_kernel(
    const float* __restrict__ h0, const float* __restrict__ Wih,
    const float* __restrict__ Whh, const float* __restrict__ Whr,
    const float* __restrict__ bih, const float* __restrict__ bhh,
    float* __restrict__ h1)
{
    int w = threadIdx.x >> 6, lane = threadIdx.x & 63;
    int p = blockIdx.x * 4 + w;
    int b = p >> 1, dir = p & 1;

    float wi0[4], wi1[4], whh[4], bias[4];
#pragma unroll
    for (int k = 0; k < 4; ++k) {
        int r = k * 64 + lane;
        wi0[k] = Wih[(size_t)(dir * 256 + r) * 2 + 0];
        wi1[k] = Wih[(size_t)(dir * 256 + r) * 2 + 1];
        whh[k] = Whh[dir * 256 + r];
        bias[k] = bih[dir * 256 + r] + bhh[dir * 256 + r];
    }
    float whr = Whr[dir * HID + lane];
    float h = 0.0f, c = 0.0f;
    const float* hb = h0 + (size_t)b * TLEN * 2;

    auto xat = [&](int t) -> float2 {
        int tc = t < TLEN ? t : TLEN - 1;
        int tt = dir ? (TLEN - 1 - tc) : tc;
        return *(const float2*)(hb + (size_t)tt * 2);
    };

    float2 xA = xat(0), xB = xat(1);
    for (int t = 0; t < TLEN; t += 2) {
        float2 xC = xat(t + 2), xD = xat(t + 3);
        {
            float g[4];
#pragma unroll
            for (int k = 0; k < 4; ++k)
                g[k] = fmaf(whh[k], h, fmaf(wi1[k], xA.y, fmaf(wi0[k], xA.x, bias[k])));
            c = sigm(g[1]) * c + sigm(g[0]) * tanh_f(g[2]);
            float pp = sigm(g[3]) * tanh_f(c) * whr;
#pragma unroll
            for (int off = 1; off < 64; off <<= 1) pp += __shfl_xor(pp, off, 64);
            h = pp;
            int tt = dir ? (TLEN - 1 - t) : t;
            if (lane == 0) h1[((size_t)b * TLEN + tt) * 2 + dir] = h;
        }
        {
            float g[4];
#pragma unroll
            for (int k = 0; k < 4; ++k)
                g[k] = fmaf(whh[k], h, fmaf(wi1[k], xB.y, fmaf(wi0[k], xB.x, bias[k])));
            c = sigm(g[1]) * c + sigm(g[0]) * tanh_f(g[2]);
            float pp = sigm(g[3]) * tanh_f(c) * whr;
#pragma unroll
            for (int off = 1; off < 64; off <<= 1) pp += __shfl_xor(pp, off, 64);
            h = pp;
            int tt = dir ? (TLEN - 2 - t) : (t + 1);
            if (lane == 0) h1[((size_t)b * TLEN + tt) * 2 + dir] = h;
        }
        xA = xC; xB = xD;
    }
}

__global__ __launch_bounds__(256) void mean_kernel(
    const float2* __restrict__ h1, float* __restrict__ out)
{
    int i = blockIdx.x * 256 + threadIdx.x;
    if (i < BATCH * TLEN) {
        float2 v = h1[i];
        out[i] = 0.5f * (v.x + v.y);
    }
}

// ===========================================================================
// FALLBACK PATH (round-2 kernels) — used only if ws_size is too small
// ===========================================================================
__global__ __launch_bounds__(256) void embed_kernel(
    const float* __restrict__ num, const int* __restrict__ cat,
    const float* __restrict__ tab, const int* __restrict__ bi,
    const int* __restrict__ ti, const float* __restrict__ W,
    const float* __restrict__ bvec, float* __restrict__ feat,
    int n_num, int n_cat)
{
    int e = blockIdx.x * 4 + (threadIdx.x >> 6);
    int hh = threadIdx.x & 63;
    if (e >= NEV) return;
    float acc = bvec[hh];
    int j = 0;
    for (int c = 0; c < n_cat; ++c) {
        int idx = cat[e * n_cat + c];
        const float* trow = tab + (size_t)idx * 8;
#pragma unroll
        for (int u = 0; u < 8; ++u)
            acc = fmaf(trow[u], W[(j + u) * HID + hh], acc);
        j += 8;
    }
    for (int u = 0; u < n_num; ++u)
        acc = fmaf(num[(size_t)e * n_num + u], W[(j + u) * HID + hh], acc);
    int pos = bi[e] * TLEN + ti[e];
    feat[(size_t)pos * HID + hh] = acc;
}

__global__ __launch_bounds__(256, 2) void lstm0_kernel(
    const float* __restrict__ feat, const float* __restrict__ Wih,
    const float* __restrict__ Whh, const float* __restrict__ Whr,
    const float* __restrict__ bih, const float* __restrict__ bhh,
    float* __restrict__ h0)
{
    const int b0 = blockIdx.x * 4;
    const int dir = blockIdx.y;
    const int tid = threadIdx.x, lane = tid & 63, wv = tid >> 6;

    const float* wrow = Wih + (size_t)(dir * 256 + tid) * HID;
    float4 w[16];
#pragma unroll
    for (int i = 0; i < 16; ++i) w[i] = ((const float4*)wrow)[i];
    const float whh = Whh[dir * 256 + tid];
    const float bias = bih[dir * 256 + tid] + bhh[dir * 256 + tid];
    const float whr = Whr[dir * HID + lane];

    __shared__ float4 featb[2][4][16];
    __shared__ float gbuf[4][256];
    __shared__ __align__(16) float hbuf[4];

    float c = 0.0f;
    const float* fb = feat + (size_t)(b0 + wv) * TLEN * HID;
    float* h0b = h0 + ((size_t)(b0 + wv) * TLEN) * 2 + dir;

    const int t0 = dir ? (TLEN - 1) : 0;
    ((float*)featb[0][wv])[lane] = fb[(size_t)t0 * HID + lane];
    if (tid < 4) hbuf[tid] = 0.0f;
    __syncthreads();

    for (int t = 0; t < TLEN; ++t) {
        const int buf = t & 1;
        const int tt = dir ? (TLEN - 1 - t) : t;
        float nf = 0.0f;
        const int tn = dir ? (TLEN - 2 - t) : (t + 1);
        const bool pf = (t < TLEN - 1);
        if (pf) nf = fb[(size_t)tn * HID + lane];
        const float4 hp = *(const float4*)hbuf;
        float a0 = fmaf(whh, hp.x, bias);
        float a1 = fmaf(whh, hp.y, bias);
        float a2 = fmaf(whh, hp.z, bias);
        float a3 = fmaf(whh, hp.w, bias);
#pragma unroll
        for (int i = 0; i < 16; ++i) {
            float4 f0 = featb[buf][0][i];
            float4 f1 = featb[buf][1][i];
            float4 f2 = featb[buf][2][i];
            float4 f3 = featb[buf][3][i];
            a0 = fmaf(f0.x, w[i].x, a0); a0 = fmaf(f0.y, w[i].y, a0);
            a0 = fmaf(f0.z, w[i].z, a0); a0 = fmaf(f0.w, w[i].w, a0);
            a1 = fmaf(f1.x, w[i].x, a1); a1 = fmaf(f1.y, w[i].y, a1);
            a1 = fmaf(f1.z, w[i].z, a1); a1 = fmaf(f1.w, w[i].w, a1);
            a2 = fmaf(f2.x, w[i].x, a2); a2 = fmaf(f2.y, w[i].y, a2);
            a2 = fmaf(f2.z, w[i].z, a2); a2 = fmaf(f2.w, w[i].w, a2);
            a3 = fmaf(f3.x, w[i].x, a3); a3 = fmaf(f3.y, w[i].y, a3);
            a3 = fmaf(f3.z, w[i].z, a3); a3 = fmaf(f3.w, w[i].w, a3);
        }
        gbuf[0][tid] = a0;
        gbuf[1][tid] = a1;
        gbuf[2][tid] = a2;
        gbuf[3][tid] = a3;
        if (pf) ((float*)featb[1 - buf][wv])[lane] = nf;
        __syncthreads();
        const float gi = gbuf[wv][lane];
        const float gf = gbuf[wv][64 + lane];
        const float gg = gbuf[wv][128 + lane];
        const float go = gbuf[wv][192 + lane];
        c = sigm(gf) * c + sigm(gi) * tanh_f(gg);
        float p = sigm(go) * tanh_f(c) * whr;
#pragma unroll
        for (int off = 1; off < 64; off <<= 1) p += __shfl_xor(p, off, 64);
        if (lane == 0) {
            hbuf[wv] = p;
            h0b[(size_t)tt * 2] = p;
        }
        __syncthreads();
    }
}

// ===========================================================================
extern "C" void kernel_launch(void* const* d_in, const int* in_sizes, int n_in,
                              void* d_out, int out_size, void* d_ws, size_t ws_size,
                              hipStream_t stream)
{
    const float* ccba_num = (const float*)d_in[0];
    const int*   ccba_bi  = (const int*)d_in[1];
    const int*   ccba_ti  = (const int*)d_in[2];
    const float* ccba_W   = (const float*)d_in[3];
    const float* ccba_b   = (const float*)d_in[4];
    const float* cdtx_num = (const float*)d_in[5];
    const int*   cdtx_cat = (const int*)d_in[6];
    const float* cdtx_tab = (const float*)d_in[7];
    const int*   cdtx_bi  = (const int*)d_in[8];
    const int*   cdtx_ti  = (const int*)d_in[9];
    const float* cdtx_W   = (const float*)d_in[10];
    const float* cdtx_b   = (const float*)d_in[11];
    const float* cust_num = (const float*)d_in[12];
    const int*   cust_cat = (const int*)d_in[13];
    const float* cust_tab = (const float*)d_in[14];
    const int*   cust_bi  = (const int*)d_in[15];
    const int*   cust_ti  = (const int*)d_in[16];
    const float* cust_W   = (const float*)d_in[17];
    const float* cust_b   = (const float*)d_in[18];
    const float* dp_num   = (const float*)d_in[19];
    const int*   dp_cat   = (const int*)d_in[20];
    const float* dp_tab   = (const float*)d_in[21];
    const int*   dp_bi    = (const int*)d_in[22];
    const int*   dp_ti    = (const int*)d_in[23];
    const float* dp_W     = (const float*)d_in[24];
    const float* dp_b     = (const float*)d_in[25];
    const float* remit_num = (const float*)d_in[26];
    const int*   remit_cat = (const int*)d_in[27];
    const float* remit_tab = (const float*)d_in[28];
    const int*   remit_bi  = (const int*)d_in[29];
    const int*   remit_ti  = (const int*)d_in[30];
    const float* remit_W   = (const float*)d_in[31];
    const float* remit_b   = (const float*)d_in[32];
    const float* Wih0 = (const float*)d_in[33];
    const float* Whh0 = (const float*)d_in[34];
    const float* Whr0 = (const float*)d_in[35];
    const float* bih0 = (const float*)d_in[36];
    const float* bhh0 = (const float*)d_in[37];
    const float* Wih1 = (const float*)d_in[38];
    const float* Whh1 = (const float*)d_in[39];
    const float* Whr1 = (const float*)d_in[40];
    const float* bih1 = (const float*)d_in[41];
    const float* bhh1 = (const float*)d_in[42];

    float* out = (float*)d_out;
    dim3 blk(256);

    const size_t GPRE_BYTES = (size_t)512000 * 512 * 4;        // 1,048,576,000
    const size_t H0_OFF = GPRE_BYTES;
    const size_t H1_OFF = H0_OFF + 4096000;
    const size_t WP_OFF = H1_OFF + 4096000;
    const size_t NEED   = WP_OFF + 130 * 512 * 4;

    if (ws_size >= NEED) {
        // ---- composed-projection path ----
        char* ws = (char*)d_ws;
        float* gpre = (float*)ws;
        float* h0   = (float*)(ws + H0_OFF);
        float* h1   = (float*)(ws + H1_OFF);
        float* wp   = (float*)(ws + WP_OFF);

        compose_kernel<<<130, 512, 0, stream>>>(
            ccba_W, ccba_b, cdtx_W, cdtx_b, cust_W, cust_b,
            dp_W, dp_b, remit_W, remit_b, Wih0, bih0, bhh0, wp);

        project_kernel<8, 0><<<512, 512, 0, stream>>>(ccba_num, nullptr, nullptr, ccba_bi, ccba_ti, wp + (size_t)0 * 512, gpre);
        project_kernel<1, 2><<<512, 512, 0, stream>>>(cdtx_num, cdtx_cat, cdtx_tab, cdtx_bi, cdtx_ti, wp + (size_t)9 * 512, gpre);
        project_kernel<1, 3><<<512, 512, 0, stream>>>(cust_num, cust_cat, cust_tab, cust_bi, cust_ti, wp + (size_t)27 * 512, gpre);
        project_kernel<2, 8><<<512, 512, 0, stream>>>(dp_num, dp_cat, dp_tab, dp_bi, dp_ti, wp + (size_t)53 * 512, gpre);
        project_kernel<1, 1><<<512, 512, 0, stream>>>(remit_num, remit_cat, remit_tab, remit_bi, remit_ti, wp + (size_t)120 * 512, gpre);

        rec0_kernel<<<500, blk, 0, stream>>>(gpre, Whh0, Whr0, h0);
        lstm1_kernel<<<500, blk, 0, stream>>>(h0, Wih1, Whh1, Whr1, bih1, bhh1, h1);
        mean_kernel<<<(BATCH * TLEN + 255) / 256, blk, 0, stream>>>((const float2*)h1, out);
    } else {
        // ---- fallback: round-2 path ----
        char* ws = (char*)d_ws;
        float* feat = (float*)ws;
        float* h0   = (float*)(ws + 131072000);
        float* h1   = (float*)(ws + 135168000);
        int eg = (NEV + 3) / 4;
        embed_kernel<<<eg, blk, 0, stream>>>(ccba_num, nullptr, nullptr, ccba_bi, ccba_ti, ccba_W, ccba_b, feat, 8, 0);
        embed_kernel<<<eg, blk, 0, stream>>>(cdtx_num, cdtx_cat, cdtx_tab, cdtx_bi, cdtx_ti, cdtx_W, cdtx_b, feat, 1, 2);
        embed_kernel<<<eg, blk, 0, stream>>>(cust_num, cust_cat, cust_tab, cust_bi, cust_ti, cust_W, cust_b, feat, 1, 3);
        embed_kernel<<<eg, blk, 0, stream>>>(dp_num, dp_cat, dp_tab, dp_bi, dp_ti, dp_W, dp_b, feat, 2, 8);
        embed_kernel<<<eg, blk, 0, stream>>>(remit_num, remit_cat, remit_tab, remit_bi, remit_ti, remit_W, remit_b, feat, 1, 1);
        lstm0_kernel<<<dim3(BATCH / 4, 2), blk, 0, stream>>>(feat, Wih0, Whh0, Whr0, bih0, bhh0, h0);
        lstm1_kernel<<<500, blk, 0, stream>>>(h0, Wih1, Whh1, Whr1, bih1, bhh1, h1);
        mean_kernel<<<(BATCH * TLEN + 255) / 256, blk, 0, stream>>>((const float2*)h1, out);
    }
}